// Round 11
// baseline (5947.151 us; speedup 1.0000x reference)
//
#include <hip/hip_runtime.h>
#include <hip/hip_bf16.h>

typedef __bf16 bf16;
typedef __bf16 bf16x8 __attribute__((ext_vector_type(8)));
typedef float f32x4 __attribute__((ext_vector_type(4)));

#define N_ROWS   512      // rows 0..255 seq1, 256..511 seq2
#define HID      1024
#define KX       320      // EMB=300 padded to 320
#define KTOT     1344     // 320 + 1024
#define NSTEPS   128
#define EMB_D    300
#define HC_W     3332     // 1025+1025+1+1025+256

// workspace layout (bytes)
#define WBT_OFF   0UL          // bf16 [4096][1344]  (packed, transposed)
#define XB_OFF    11010048UL   // bf16 [128][512][320]
#define HB_OFF    52953088UL   // bf16 [2][512][1024]
#define BIASP_OFF 55050240UL   // f32  [4096] (packed order)
#define HC_OFF    55066624UL   // f32  [256][3332]
#define H2T_OFF   58478592UL   // f32  [1025][256]
#define T1_OFF    59528192UL   // f32  [256][1025]
#define E1_OFF    60577792UL   // f32  [256][512]
// barrier region (dwords from BAR_OFF):
//   ga[g]   at dword g*16   (g=0..7)   8 monotonic arrive lines, 64B apart
//   gsum    at dword 128               monotonic summary line
//   flag[t] at dword 256 + t*16        per-step flag lines (fresh each step)
#define BAR_OFF   61102080UL

// ENVELOPE RULE (10 rounds of evidence): cooperative kernel must keep
// LDS <= 61 KB and compiler VGPR <= 128, else hipLaunchCooperativeKernel
// silently fails (r3: 139KB LDS, r4: ~380 VGPR, r10: 80KB LDS all no-op'd).

__device__ __forceinline__ float sigm(float x) { return 1.f / (1.f + __expf(-x)); }
__device__ __forceinline__ float tanh_fast(float x) {
  float xc = fminf(fmaxf(x, -15.f), 15.f);
  float e = __expf(2.f * xc);
  return (e - 1.f) / (e + 1.f);
}

// ---- pack kernels -------------------------------------------------------
// packed gate-col order: p = cbk*128 + g*32 + c  <->  orig col g*1024 + cbk*32 + c
__global__ void pack_wbt(const float* __restrict__ lk, bf16* __restrict__ wbt) {
  int p = blockIdx.x * 256 + threadIdx.x;   // 0..4095
  int k = blockIdx.y;                        // 0..1343
  int cbk = p >> 7, g = (p >> 5) & 3, c = p & 31;
  int oc = g * HID + cbk * 32 + c;
  float v = 0.f;
  if (k < KX) { if (k < EMB_D) v = lk[(size_t)k * 4096 + oc]; }
  else v = lk[(size_t)(EMB_D + k - KX) * 4096 + oc];
  wbt[(size_t)p * KTOT + k] = (bf16)v;
}

// r11: vectorized bf16x8 writes; block 320 = 8 timesteps x 40 e-groups
__global__ void pack_xb(const int* __restrict__ in1, const int* __restrict__ in2,
                        const float* __restrict__ emb, bf16* __restrict__ xb) {
  int r = blockIdx.x;                        // 0..511
  int t = blockIdx.y * 8 + threadIdx.x / 40; // 0..127
  int e8 = threadIdx.x % 40;                 // 0..39 (8 elems each)
  int tok = (r < 256) ? in1[r * 128 + t] : in2[(r - 256) * 128 + t];
  const float* er = emb + (size_t)tok * EMB_D + e8 * 8;
  bf16x8 v;
  if (e8 < 37) {                             // e8*8+7 = 303? no: 36*8+7=295 < 300
#pragma unroll
    for (int i = 0; i < 8; ++i) v[i] = (bf16)er[i];
  } else {
#pragma unroll
    for (int i = 0; i < 8; ++i) {
      int e = e8 * 8 + i;
      v[i] = (e < EMB_D) ? (bf16)er[i] : (bf16)0.f;
    }
  }
  *reinterpret_cast<bf16x8*>(&xb[((size_t)t * N_ROWS + r) * KX + e8 * 8]) = v;
}

__global__ void pack_misc(const float* __restrict__ h1i, const float* __restrict__ h2i,
                          const float* __restrict__ bias, bf16* __restrict__ hb0,
                          float* __restrict__ biasp, unsigned* __restrict__ bar) {
  int idx = blockIdx.x * 256 + threadIdx.x;
  if (idx < N_ROWS * HID) {
    int r = idx >> 10, k = idx & 1023;
    float v = (r < 256) ? h1i[(size_t)r * HID + k] : h2i[(size_t)(r - 256) * HID + k];
    hb0[idx] = (bf16)v;
  }
  if (idx < 4096) {
    int cbk = idx >> 7, g = (idx >> 5) & 3, c = idx & 31;
    biasp[idx] = bias[g * HID + cbk * 32 + c];
    bar[idx] = 0u;   // reset all barrier lines (16 KB region) every launch
  }
}

// ---- cooperative LSTM recurrence ---------------------------------------
// grid 256 = 8 row-blocks x 32 cell-col-blocks (r6/r9-proven mapping).
// wave w owns rows w*16..w*16+15, ALL 128 packed cols (no gate exchange):
//   acc[ni][q] = G[row=w*16+(lane>>4)*4+q][pcol=ni*16+(lane&15)], g=ni>>1
// r11 = r9 + depth-2 register-slot pipeline (r7-proven schedule): loads
// issued 3 chunks ahead, ds_write 1 chunk ahead (2-iter latency cover).
// Cross-step slot parity processes chunks in order 0,2,1,3..20 (order-
// invariant accumulation; swapped chunks 1,2 are x-data, h-safe) [r7 pass].
// r9-proven hierarchical single-acquire barrier; wait at kc==2, just
// before the first h-load ISSUE (NK=5 issued that iteration).
struct Slot { bf16x8 a0, a1, b[4]; };

__launch_bounds__(256, 2)
__global__ void lstm_coop(const bf16* __restrict__ xb, const bf16* __restrict__ wbt,
                          bf16* __restrict__ hb, const float* __restrict__ biasp,
                          const float* __restrict__ c1i, const float* __restrict__ c2i,
                          const int* __restrict__ s1, const int* __restrict__ s2,
                          unsigned* __restrict__ bar) {
  __shared__ bf16 As[2][64][64];     // 16 KB, XOR-swizzled 16B chunks
  __shared__ bf16 Bs[2][128][64];    // 32 KB  (total 48 KB: in envelope)
  const int tid = threadIdx.x;
  const int wave = tid >> 6;
  const int lane = tid & 63;
  const int lrow = lane & 15;
  const int hi = lane >> 4;        // 0..3
  const int l7 = lane & 7;
  const int bid = blockIdx.x;
  const int rb = bid >> 5;
  const int cbk = bid & 31;
  const int r0 = rb * 64;

  const int rowbase = r0 + wave * 16 + hi * 4;   // + q (q=0..3)
  const int cell0 = cbk * 32 + lrow;             // + 16*e (e=0..1)

  int slen[4];
#pragma unroll
  for (int q = 0; q < 4; ++q) {
    int rr = rowbase + q;
    slen[q] = (rr < 256) ? s1[rr] : s2[rr - 256];
  }

  float creg[2][4];   // [e][q], stays f32 in registers
  {
    const float* cb = (rowbase < 256) ? c1i : c2i;
    const int radj = (rowbase < 256) ? rowbase : rowbase - 256;
#pragma unroll
    for (int e = 0; e < 2; ++e)
#pragma unroll
      for (int q = 0; q < 4; ++q)
        creg[e][q] = cb[(size_t)(radj + q) * HID + cell0 + e * 16];
  }

  // bias folded into accumulator init: acc[ni] col = ni*16+lrow (col-only dep)
  float bv[8];
#pragma unroll
  for (int ni = 0; ni < 8; ++ni)
    bv[ni] = biasp[cbk * 128 + ni * 16 + lrow];

  const bf16* wsrc = wbt + (size_t)(cbk * 128) * KTOT;

  // staging thread mapping (r2-proven swizzles)
  const int a_r = tid >> 2, a_c = tid & 3;
  const int b_r8 = tid >> 3, b_c = tid & 7;
  const int asw0 = ((a_c       ^ (a_r & 7)) << 3);
  const int asw1 = (((a_c + 4) ^ (a_r & 7)) << 3);
  const int bsw  = ((b_c ^ (b_r8 & 7)) << 3);     // +32q keeps row&7 constant

  Slot sl[2];
  auto issue_loads = [&](int nt, int nkc, Slot& s) {
    const bf16* asrc = (nkc < 5)
        ? (xb + ((size_t)nt * N_ROWS + r0 + a_r) * KX + nkc * 64 + a_c * 8)
        : (hb + ((size_t)(nt & 1) << 19) + ((size_t)(r0 + a_r) << 10) +
           (nkc * 64 - KX) + a_c * 8);
    s.a0 = *reinterpret_cast<const bf16x8*>(asrc);
    s.a1 = *reinterpret_cast<const bf16x8*>(asrc + 32);
    const bf16* bsrc = wsrc + (size_t)b_r8 * KTOT + nkc * 64 + b_c * 8;
#pragma unroll
    for (int q = 0; q < 4; ++q)
      s.b[q] = *reinterpret_cast<const bf16x8*>(bsrc + (size_t)(32 * q) * KTOT);
  };

  // prologue: buf0 <- chunk 0 (t=0, x); slot1 <- chunk 1; slot0 <- chunk 2
  issue_loads(0, 0, sl[0]);
  *reinterpret_cast<bf16x8*>(&As[0][a_r][asw0]) = sl[0].a0;
  *reinterpret_cast<bf16x8*>(&As[0][a_r][asw1]) = sl[0].a1;
#pragma unroll
  for (int q = 0; q < 4; ++q)
    *reinterpret_cast<bf16x8*>(&Bs[0][b_r8 + 32 * q][bsw]) = sl[0].b[q];
  issue_loads(0, 1, sl[1]);
  issue_loads(0, 2, sl[0]);
  __syncthreads();
  int db = 0;

  unsigned* ga    = bar + (bid & 7) * 16;   // own group arrive line (64B apart)
  unsigned* gsum  = bar + 128;              // summary line
  unsigned* flags = bar + 256;              // flag[t] at flags + t*16

  for (int t = 0; t < NSTEPS; ++t) {
    f32x4 acc[8];
#pragma unroll
    for (int ni = 0; ni < 8; ++ni)
      acc[ni] = f32x4{bv[ni], bv[ni], bv[ni], bv[ni]};

    // iter KC: ds_write chunk KC+1 from slot (KC+1)&1; refill slot with
    // chunk KC+3 (wraps to next step's x chunks); compute chunk KC's buf.
#define CHUNK(KC)                                                              \
    {                                                                          \
      constexpr int S = ((KC) + 1) & 1;                                        \
      *reinterpret_cast<bf16x8*>(&As[db ^ 1][a_r][asw0]) = sl[S].a0;           \
      *reinterpret_cast<bf16x8*>(&As[db ^ 1][a_r][asw1]) = sl[S].a1;           \
      _Pragma("unroll")                                                        \
      for (int q = 0; q < 4; ++q)                                              \
        *reinterpret_cast<bf16x8*>(&Bs[db ^ 1][b_r8 + 32 * q][bsw]) = sl[S].b[q]; \
      if constexpr ((KC) == 2) {                                               \
        if (t > 0) {                                                           \
          if (tid == 0) {                                                      \
            const unsigned* fl = flags + (t - 1) * 16;                         \
            while (__hip_atomic_load(fl, __ATOMIC_RELAXED,                     \
                                     __HIP_MEMORY_SCOPE_AGENT) == 0u)          \
              __builtin_amdgcn_s_sleep(2);                                     \
            (void)__hip_atomic_load(fl, __ATOMIC_ACQUIRE,                      \
                                    __HIP_MEMORY_SCOPE_AGENT);                 \
          }                                                                    \
          __syncthreads();                                                     \
        }                                                                      \
      }                                                                        \
      {                                                                        \
        constexpr int NK = ((KC) >= 18) ? ((KC) + 3 - 21) : ((KC) + 3);        \
        const int nt = ((KC) >= 18) ? (t + 1) : t;                             \
        if (nt < NSTEPS) issue_loads(nt, NK, sl[S]);                           \
      }                                                                        \
      _Pragma("unroll")                                                        \
      for (int ks = 0; ks < 2; ++ks) {                                         \
        const int cs = (((ks << 2) | hi) ^ l7) << 3;                           \
        bf16x8 af = *reinterpret_cast<const bf16x8*>(&As[db][wave * 16 + lrow][cs]); \
        _Pragma("unroll")                                                      \
        for (int ni = 0; ni < 8; ++ni) {                                       \
          bf16x8 bfv = *reinterpret_cast<const bf16x8*>(&Bs[db][ni * 16 + lrow][cs]); \
          acc[ni] = __builtin_amdgcn_mfma_f32_16x16x32_bf16(af, bfv, acc[ni], 0, 0, 0); \
        }                                                                      \
      }                                                                        \
      __syncthreads();                                                         \
      db ^= 1;                                                                 \
    }

    CHUNK(0)  CHUNK(1)  CHUNK(2)  CHUNK(3)  CHUNK(4)  CHUNK(5)  CHUNK(6)
    CHUNK(7)  CHUNK(8)  CHUNK(9)  CHUNK(10) CHUNK(11) CHUNK(12) CHUNK(13)
    CHUNK(14) CHUNK(15) CHUNK(16) CHUNK(17) CHUNK(18) CHUNK(19) CHUNK(20)
#undef CHUNK

    // cell update: fully in-register (g = ni>>1, cc = (ni&1)*16 + lrow)
    {
      const size_t curo = (size_t)(t & 1) << 19;
      const bf16* hc = hb + curo;
      bf16* hnb = hb + (curo ^ ((size_t)1 << 19));
#pragma unroll
      for (int e = 0; e < 2; ++e)
#pragma unroll
        for (int q = 0; q < 4; ++q) {
          float ig = acc[0 + e][q];
          float jg = acc[2 + e][q];
          float fg = acc[4 + e][q];
          float og = acc[6 + e][q];
          float cn = sigm(fg + 1.f) * creg[e][q] + sigm(ig) * tanh_fast(jg);
          float hv = tanh_fast(cn) * sigm(og);
          size_t off = ((size_t)(rowbase + q) << 10) + cell0 + e * 16;
          float ho;
          if (t < slen[q]) { creg[e][q] = cn; ho = hv; }
          else ho = (float)hc[off];
          hnb[off] = (bf16)ho;
        }
    }

    // arrive: drain h stores (syncthreads emits vmcnt(0)), then hierarchical
    // release chain: ga (32 fan-in, RELEASE) -> gsum (8 fan-in) -> flag[t].
    __syncthreads();
    if (t < NSTEPS - 1 && tid == 0) {
      unsigned prev = __hip_atomic_fetch_add(ga, 1u, __ATOMIC_RELEASE,
                                             __HIP_MEMORY_SCOPE_AGENT);
      if ((prev & 31u) == 31u) {        // 32nd arrival of this step on this line
        (void)__hip_atomic_load(ga, __ATOMIC_ACQUIRE, __HIP_MEMORY_SCOPE_AGENT);
        unsigned p2 = __hip_atomic_fetch_add(gsum, 1u, __ATOMIC_RELEASE,
                                             __HIP_MEMORY_SCOPE_AGENT);
        if ((p2 & 7u) == 7u) {          // all 8 groups done
          (void)__hip_atomic_load(gsum, __ATOMIC_ACQUIRE, __HIP_MEMORY_SCOPE_AGENT);
          __hip_atomic_store(flags + t * 16, 1u, __ATOMIC_RELEASE,
                             __HIP_MEMORY_SCOPE_AGENT);
        }
      }
    }
  }
}

// ---- head ---------------------------------------------------------------
__global__ void feat_kernel(const bf16* __restrict__ hb0, const int* __restrict__ s1,
                            const int* __restrict__ s2, float* __restrict__ HC,
                            float* __restrict__ H2T) {
  int a = blockIdx.x;
  int tid = threadIdx.x;
  __shared__ float red[256];
  const bf16* h1r = hb0 + (size_t)a * HID;
  const bf16* h2r = hb0 + (size_t)(a + 256) * HID;
  float l1 = (float)s1[a] * (1.f / 128.f);
  float l2 = (float)s2[a] * (1.f / 128.f);
  float dacc = 0.f;
  for (int k = tid; k < 1025; k += 256) {
    float v1 = (k < HID) ? (float)h1r[k] : l1;
    float v2 = (k < HID) ? (float)h2r[k] : l2;
    HC[(size_t)a * HC_W + k] = v1;
    HC[(size_t)a * HC_W + 1025 + k] = v2;
    HC[(size_t)a * HC_W + 2051 + k] = v1 * v2;
    H2T[(size_t)k * 256 + a] = v2;
    float d = v1 - v2;
    dacc += d * d;
  }
  red[tid] = dacc;
  __syncthreads();
  for (int s = 128; s > 0; s >>= 1) {
    if (tid < s) red[tid] += red[tid + s];
    __syncthreads();
  }
  if (tid == 0) HC[(size_t)a * HC_W + 2050] = red[0];
}

// r11: 8 rows/block (grid 5 x 32) instead of 32 rows (grid 5 x 8) — 4x blocks
__global__ void t1_kernel(const float* __restrict__ HC, const float* __restrict__ Wh,
                          float* __restrict__ T1) {
  int j = blockIdx.x * 256 + threadIdx.x;
  int a0 = blockIdx.y * 8;
  __shared__ float sh[8][64];
  float acc[8];
#pragma unroll
  for (int r = 0; r < 8; ++r) acc[r] = 0.f;
  for (int kc = 0; kc < 1025; kc += 64) {
    int kn = (1025 - kc < 64) ? (1025 - kc) : 64;
    for (int idx = threadIdx.x; idx < 512; idx += 256) {
      int r = idx >> 6, kk = idx & 63;
      sh[r][kk] = (kk < kn) ? HC[(size_t)(a0 + r) * HC_W + kc + kk] : 0.f;
    }
    __syncthreads();
    if (j < 1025) {
      for (int kk = 0; kk < kn; ++kk) {
        float w = Wh[(size_t)(kc + kk) * 1025 + j];
#pragma unroll
        for (int r = 0; r < 8; ++r) acc[r] += sh[r][kk] * w;
      }
    }
    __syncthreads();
  }
  if (j < 1025) {
    for (int r = 0; r < 8; ++r) T1[(size_t)(a0 + r) * 1025 + j] = acc[r];
  }
}

__global__ void inter_kernel(const float* __restrict__ T1, const float* __restrict__ H2T,
                             float* __restrict__ HC) {
  int a0 = blockIdx.x * 8;
  int b = threadIdx.x;
  __shared__ float sT[8][1025];
  for (int idx = threadIdx.x; idx < 8 * 1025; idx += 256) {
    int r = idx / 1025, k = idx - r * 1025;
    sT[r][k] = T1[(size_t)(a0 + r) * 1025 + k];
  }
  __syncthreads();
  float acc[8];
#pragma unroll
  for (int r = 0; r < 8; ++r) acc[r] = 0.f;
  for (int k = 0; k < 1025; ++k) {
    float v = H2T[(size_t)k * 256 + b];
#pragma unroll
    for (int r = 0; r < 8; ++r) acc[r] += sT[r][k] * v;
  }
#pragma unroll
  for (int r = 0; r < 8; ++r)
    HC[(size_t)(a0 + r) * HC_W + 3076 + b] = acc[r];
}

__global__ void e1_kernel(const float* __restrict__ HC, const float* __restrict__ W1,
                          const float* __restrict__ b1, float* __restrict__ E1) {
  int a0 = blockIdx.x * 8;
  int j = blockIdx.y * 256 + threadIdx.x;
  __shared__ float sh[8][128];
  float acc[8];
#pragma unroll
  for (int r = 0; r < 8; ++r) acc[r] = 0.f;
  for (int kc = 0; kc < HC_W; kc += 128) {
    int kn = (HC_W - kc < 128) ? (HC_W - kc) : 128;
    for (int idx = threadIdx.x; idx < 1024; idx += 256) {
      int r = idx >> 7, kk = idx & 127;
      sh[r][kk] = (kk < kn) ? HC[(size_t)(a0 + r) * HC_W + kc + kk] : 0.f;
    }
    __syncthreads();
    for (int kk = 0; kk < kn; ++kk) {
      float w = W1[(size_t)(kc + kk) * 512 + j];
#pragma unroll
      for (int r = 0; r < 8; ++r) acc[r] += sh[r][kk] * w;
    }
    __syncthreads();
  }
  float bj = b1[j];
#pragma unroll
  for (int r = 0; r < 8; ++r)
    E1[(size_t)(a0 + r) * 512 + j] = fmaxf(acc[r] + bj, 0.f);
}

__global__ void out_kernel(const float* __restrict__ E1, const float* __restrict__ W2,
                           const float* __restrict__ b2, float* __restrict__ out) {
  int a = threadIdx.x;
  float a0 = 0.f, a1 = 0.f;
  const float* e = E1 + (size_t)a * 512;
  for (int k = 0; k < 512; ++k) {
    float v = e[k];
    a0 += v * W2[2 * k];
    a1 += v * W2[2 * k + 1];
  }
  out[2 * a] = a0 + b2[0];
  out[2 * a + 1] = a1 + b2[1];
}

// ---- host ---------------------------------------------------------------
extern "C" void kernel_launch(void* const* d_in, const int* in_sizes, int n_in,
                              void* d_out, int out_size, void* d_ws, size_t ws_size,
                              hipStream_t stream) {
  const int*   input1 = (const int*)d_in[0];
  const int*   input2 = (const int*)d_in[1];
  const int*   seql1  = (const int*)d_in[2];
  const int*   seql2  = (const int*)d_in[3];
  const float* emb    = (const float*)d_in[4];
  const float* lk     = (const float*)d_in[5];
  const float* lbias  = (const float*)d_in[6];
  const float* c1i    = (const float*)d_in[7];
  const float* h1i    = (const float*)d_in[8];
  const float* c2i    = (const float*)d_in[9];
  const float* h2i    = (const float*)d_in[10];
  const float* W_h    = (const float*)d_in[11];
  const float* W1     = (const float*)d_in[12];
  const float* b1     = (const float*)d_in[13];
  const float* W2     = (const float*)d_in[14];
  const float* b2     = (const float*)d_in[15];

  char* ws = (char*)d_ws;
  bf16*     WbT   = (bf16*)(ws + WBT_OFF);
  bf16*     Xb    = (bf16*)(ws + XB_OFF);
  bf16*     Hb    = (bf16*)(ws + HB_OFF);
  float*    biasp = (float*)(ws + BIASP_OFF);
  float*    HC    = (float*)(ws + HC_OFF);
  float*    H2T   = (float*)(ws + H2T_OFF);
  float*    T1    = (float*)(ws + T1_OFF);
  float*    E1    = (float*)(ws + E1_OFF);
  unsigned* bar   = (unsigned*)(ws + BAR_OFF);

  pack_wbt<<<dim3(16, 1344), 256, 0, stream>>>(lk, WbT);
  pack_xb<<<dim3(512, 16), 320, 0, stream>>>(input1, input2, emb, Xb);
  pack_misc<<<2048, 256, 0, stream>>>(h1i, h2i, lbias, Hb, biasp, bar);

  void* kargs[] = { (void*)&Xb, (void*)&WbT, (void*)&Hb, (void*)&biasp,
                    (void*)&c1i, (void*)&c2i, (void*)&seql1, (void*)&seql2,
                    (void*)&bar };
  hipLaunchCooperativeKernel((void*)lstm_coop, dim3(256), dim3(256), kargs, 0, stream);

  feat_kernel<<<256, 256, 0, stream>>>(Hb, seql1, seql2, HC, H2T);
  t1_kernel<<<dim3(5, 32), 256, 0, stream>>>(HC, W_h, T1);
  inter_kernel<<<32, 256, 0, stream>>>(T1, H2T, HC);
  e1_kernel<<<dim3(32, 2), 256, 0, stream>>>(HC, W1, b1, E1);
  out_kernel<<<1, 256, 0, stream>>>(E1, W2, b2, (float*)d_out);
}

// Round 13
// 3578.242 us; speedup vs baseline: 1.6620x; 1.6620x over previous
//
#include <hip/hip_runtime.h>
#include <hip/hip_bf16.h>

typedef __bf16 bf16;
typedef __bf16 bf16x8 __attribute__((ext_vector_type(8)));
typedef float f32x4 __attribute__((ext_vector_type(4)));

#define N_ROWS   512      // rows 0..255 seq1, 256..511 seq2
#define HID      1024
#define KX       320      // EMB=300 padded to 320
#define KTOT     1344     // 320 + 1024
#define NSTEPS   128
#define EMB_D    300
#define HC_W     3332     // 1025+1025+1+1025+256

// workspace layout (bytes)
#define WBT_OFF   0UL          // bf16 [4096][1344]  (packed p2 order, transposed)
#define XB_OFF    11010048UL   // bf16 [128][512][320]
#define HB_OFF    52953088UL   // bf16 [2][512][1024]
#define BIASP_OFF 55050240UL   // f32  [4096] (packed p2 order)
#define HC_OFF    55066624UL   // f32  [256][3332]
#define H2T_OFF   58478592UL   // f32  [1025][256]
#define T1_OFF    59528192UL   // f32  [256][1025]
#define E1_OFF    60577792UL   // f32  [256][512]
// barrier region (dwords from BAR_OFF):
//   ga[g]   at dword g*16   (g=0..7)   8 monotonic arrive lines, 64B apart
//   gsum    at dword 128               monotonic summary line
//   flag[t] at dword 256 + t*16        per-step flag lines (fresh each step)
#define BAR_OFF   61102080UL

// ENVELOPE RULE (12 rounds of evidence): the cooperative kernel must use
// __launch_bounds__(256,2) with compiled VGPR <= 128 and static LDS <= 49KB
// (all passes: r5/r6/r9/r11; all (256,1)/high-VGPR/big-LDS variants silently
// no-op the coop launch: r3,r4,r10,r12). Also: no multi-slot register staging
// arrays (r7/r8/r11 slot pipeline -> compiler remat -> 7x L2-fill blowup).

__device__ __forceinline__ float sigm(float x) { return 1.f / (1.f + __expf(-x)); }
__device__ __forceinline__ float tanh_fast(float x) {
  float xc = fminf(fmaxf(x, -15.f), 15.f);
  float e = __expf(2.f * xc);
  return (e - 1.f) / (e + 1.f);
}

// ---- pack kernels -------------------------------------------------------
// r13 packed order: p2 = cb*64 + g*16 + c  <->  orig col g*1024 + cb*16 + c
// (cb = cell/16 in 0..63, c = cell%16) — each 64-pcol group holds all 4
// gates of 16 consecutive cells.
__global__ void pack_wbt(const float* __restrict__ lk, bf16* __restrict__ wbt) {
  int p = blockIdx.x * 256 + threadIdx.x;   // 0..4095
  int k = blockIdx.y;                        // 0..1343
  int cb = p >> 6, g = (p >> 4) & 3, c = p & 15;
  int oc = g * HID + cb * 16 + c;
  float v = 0.f;
  if (k < KX) { if (k < EMB_D) v = lk[(size_t)k * 4096 + oc]; }
  else v = lk[(size_t)(EMB_D + k - KX) * 4096 + oc];
  wbt[(size_t)p * KTOT + k] = (bf16)v;
}

// vectorized bf16x8 writes; block 320 = 8 timesteps x 40 e-groups (r11-proven)
__global__ void pack_xb(const int* __restrict__ in1, const int* __restrict__ in2,
                        const float* __restrict__ emb, bf16* __restrict__ xb) {
  int r = blockIdx.x;                        // 0..511
  int t = blockIdx.y * 8 + threadIdx.x / 40; // 0..127
  int e8 = threadIdx.x % 40;                 // 0..39 (8 elems each)
  int tok = (r < 256) ? in1[r * 128 + t] : in2[(r - 256) * 128 + t];
  const float* er = emb + (size_t)tok * EMB_D + e8 * 8;
  bf16x8 v;
  if (e8 < 37) {
#pragma unroll
    for (int i = 0; i < 8; ++i) v[i] = (bf16)er[i];
  } else {
#pragma unroll
    for (int i = 0; i < 8; ++i) {
      int e = e8 * 8 + i;
      v[i] = (e < EMB_D) ? (bf16)er[i] : (bf16)0.f;
    }
  }
  *reinterpret_cast<bf16x8*>(&xb[((size_t)t * N_ROWS + r) * KX + e8 * 8]) = v;
}

__global__ void pack_misc(const float* __restrict__ h1i, const float* __restrict__ h2i,
                          const float* __restrict__ bias, bf16* __restrict__ hb0,
                          float* __restrict__ biasp, unsigned* __restrict__ bar) {
  int idx = blockIdx.x * 256 + threadIdx.x;
  if (idx < N_ROWS * HID) {
    int r = idx >> 10, k = idx & 1023;
    float v = (r < 256) ? h1i[(size_t)r * HID + k] : h2i[(size_t)(r - 256) * HID + k];
    hb0[idx] = (bf16)v;
  }
  if (idx < 4096) {
    int cb = idx >> 6, g = (idx >> 4) & 3, c = idx & 15;
    biasp[idx] = bias[g * HID + cb * 16 + c];
    bar[idx] = 0u;   // reset all barrier lines (16 KB region) every launch
  }
}

// ---- cooperative LSTM recurrence ---------------------------------------
// grid 256 = 4 row-blocks x 64 col-groups. Block: 128 rows x 64 pcols
// (= all 4 gates of 16 cells, r13 packing). Wave w owns rows w*32..+31:
//   acc[mi][ni][q] = G[row=w*32+mi*16+(lane>>4)*4+q][pcol=ni*16+(lane&15)]
//   gate = ni, cell = cb*16 + (lane&15): cell update fully in-register,
//   no gate exchange, no cross-wave reduction.
// Per-CU LDS reads 48KB/chunk (r9: 72KB): B-frag redundancy 4x (was 8x).
// Global bytes per thread unchanged (96B/chunk, 6 loads). LDS 48KB.
// Staging (single-slot regs), issue schedule (depth-1, 2 chunks ahead),
// and the r9-proven hierarchical single-acquire barrier are verbatim r9.
__launch_bounds__(256, 2)
__global__ void lstm_coop(const bf16* __restrict__ xb, const bf16* __restrict__ wbt,
                          bf16* __restrict__ hb, const float* __restrict__ biasp,
                          const float* __restrict__ c1i, const float* __restrict__ c2i,
                          const int* __restrict__ s1, const int* __restrict__ s2,
                          unsigned* __restrict__ bar) {
  __shared__ bf16 As[2][128][64];    // 32 KB, XOR-swizzled 16B chunks
  __shared__ bf16 Bs[2][64][64];     // 16 KB  (total 48 KB)
  const int tid = threadIdx.x;
  const int wave = tid >> 6;
  const int lane = tid & 63;
  const int lrow = lane & 15;
  const int hi = lane >> 4;        // 0..3
  const int l7 = lane & 7;
  const int bid = blockIdx.x;
  const int rb = bid >> 6;         // 0..3
  const int cb = bid & 63;         // 0..63
  const int r0 = rb * 128;

  const int cellabs = cb * 16 + lrow;    // this lane's cell column (orig order)

  int slen[2][4];     // per (mi,q): row = r0 + wave*32 + mi*16 + hi*4 + q
#pragma unroll
  for (int mi = 0; mi < 2; ++mi)
#pragma unroll
    for (int q = 0; q < 4; ++q) {
      int rr = r0 + wave * 32 + mi * 16 + hi * 4 + q;
      slen[mi][q] = (rr < 256) ? s1[rr] : s2[rr - 256];
    }

  float creg[2][4];   // [mi][q] cell state, f32 in registers
#pragma unroll
  for (int mi = 0; mi < 2; ++mi)
#pragma unroll
    for (int q = 0; q < 4; ++q) {
      int rr = r0 + wave * 32 + mi * 16 + hi * 4 + q;
      const float* cbp = (rr < 256) ? (c1i + (size_t)rr * HID)
                                    : (c2i + (size_t)(rr - 256) * HID);
      creg[mi][q] = cbp[cellabs];
    }

  // bias folded into accumulator init: acc[.][ni] col = ni*16+lrow = gate ni
  float bv[4];
#pragma unroll
  for (int ni = 0; ni < 4; ++ni)
    bv[ni] = biasp[cb * 64 + ni * 16 + lrow];

  // staging thread mapping: A 128 rows x 8 chunks (2 threads/row, 4 chunks
  // each); B 64 rows x 8 chunks (4 threads/row, 2 chunks each). Same XOR
  // swizzle family as r2/r9: chunk cc -> col ((cc ^ (row&7)) << 3).
  const int a_r = tid >> 1, a_cb = (tid & 1) * 4;
  const int b_r = tid >> 2, b_cb = (tid & 3) * 2;

  bf16x8 ra[4], rbv2[2];
  auto issue_loads = [&](int nt, int nkc) {
    const bf16* asrc = (nkc < 5)
        ? (xb + ((size_t)nt * N_ROWS + r0 + a_r) * KX + nkc * 64 + a_cb * 8)
        : (hb + ((size_t)(nt & 1) << 19) + ((size_t)(r0 + a_r) << 10) +
           (nkc * 64 - KX) + a_cb * 8);
#pragma unroll
    for (int q = 0; q < 4; ++q)
      ra[q] = *reinterpret_cast<const bf16x8*>(asrc + q * 8);
    const bf16* bsrc = wbt + (size_t)(cb * 64 + b_r) * KTOT + nkc * 64 + b_cb * 8;
#pragma unroll
    for (int q = 0; q < 2; ++q)
      rbv2[q] = *reinterpret_cast<const bf16x8*>(bsrc + q * 8);
  };
  auto stage_to = [&](int buf) {
#pragma unroll
    for (int q = 0; q < 4; ++q)
      *reinterpret_cast<bf16x8*>(&As[buf][a_r][((a_cb + q) ^ (a_r & 7)) << 3]) = ra[q];
#pragma unroll
    for (int q = 0; q < 2; ++q)
      *reinterpret_cast<bf16x8*>(&Bs[buf][b_r][((b_cb + q) ^ (b_r & 7)) << 3]) = rbv2[q];
  };

  // prologue: buf0 <- chunk 0 (t=0, x); regs <- chunk 1
  issue_loads(0, 0);
  stage_to(0);
  issue_loads(0, 1);
  __syncthreads();
  int db = 0;

  unsigned* ga    = bar + (bid & 7) * 16;   // own group arrive line (64B apart)
  unsigned* gsum  = bar + 128;              // summary line
  unsigned* flags = bar + 256;              // flag[t] at flags + t*16

  for (int t = 0; t < NSTEPS; ++t) {
    f32x4 acc[2][4];
#pragma unroll
    for (int mi = 0; mi < 2; ++mi)
#pragma unroll
      for (int ni = 0; ni < 4; ++ni)
        acc[mi][ni] = f32x4{bv[ni], bv[ni], bv[ni], bv[ni]};

    for (int kc = 0; kc < 21; ++kc) {
      // stage chunk kc+1 (regs invariant) into the other buffer
      stage_to(db ^ 1);

      // grid wait: peers' h(t) must be visible before the first h-load ISSUE
      // (nkc=5, issued this iteration). x-chunks 0..2 covered the latency.
      if (kc == 3 && t > 0) {
        if (tid == 0) {
          const unsigned* fl = flags + (t - 1) * 16;
          while (__hip_atomic_load(fl, __ATOMIC_RELAXED, __HIP_MEMORY_SCOPE_AGENT) == 0u)
            __builtin_amdgcn_s_sleep(2);
          (void)__hip_atomic_load(fl, __ATOMIC_ACQUIRE, __HIP_MEMORY_SCOPE_AGENT);
        }
        __syncthreads();
      }

      // issue loads for chunk kc+2 (wraps into next step's x-chunks)
      {
        int nkc = kc + 2, nt = t;
        if (nkc > 20) { nkc -= 21; ++nt; }
        if (nt < NSTEPS) issue_loads(nt, nkc);
      }

      // compute chunk kc from buf[db]: per ks, 2 A-frags + 4 B-frags, 8 MFMAs
#pragma unroll
      for (int ks = 0; ks < 2; ++ks) {
        const int cs = (((ks << 2) | hi) ^ l7) << 3;
        bf16x8 af[2], bfv[4];
#pragma unroll
        for (int mi = 0; mi < 2; ++mi)
          af[mi] = *reinterpret_cast<const bf16x8*>(
              &As[db][wave * 32 + mi * 16 + lrow][cs]);
#pragma unroll
        for (int ni = 0; ni < 4; ++ni)
          bfv[ni] = *reinterpret_cast<const bf16x8*>(&Bs[db][ni * 16 + lrow][cs]);
#pragma unroll
        for (int mi = 0; mi < 2; ++mi)
#pragma unroll
          for (int ni = 0; ni < 4; ++ni)
            acc[mi][ni] = __builtin_amdgcn_mfma_f32_16x16x32_bf16(
                af[mi], bfv[ni], acc[mi][ni], 0, 0, 0);
      }
      __syncthreads();
      db ^= 1;
    }

    // cell update: lane owns 8 rows x 1 cell, all 4 gates in-register (g=ni)
    {
      const size_t curo = (size_t)(t & 1) << 19;
      const bf16* hc = hb + curo;
      bf16* hnb = hb + (curo ^ ((size_t)1 << 19));
#pragma unroll
      for (int mi = 0; mi < 2; ++mi)
#pragma unroll
        for (int q = 0; q < 4; ++q) {
          float ig = acc[mi][0][q];
          float jg = acc[mi][1][q];
          float fg = acc[mi][2][q];
          float og = acc[mi][3][q];
          float cn = sigm(fg + 1.f) * creg[mi][q] + sigm(ig) * tanh_fast(jg);
          float hv = tanh_fast(cn) * sigm(og);
          int rr = r0 + wave * 32 + mi * 16 + hi * 4 + q;
          size_t off = ((size_t)rr << 10) + cellabs;
          float ho;
          if (t < slen[mi][q]) { creg[mi][q] = cn; ho = hv; }
          else ho = (float)hc[off];
          hnb[off] = (bf16)ho;
        }
    }

    // arrive: drain h stores (syncthreads emits vmcnt(0)), then hierarchical
    // release chain: ga (32 fan-in, RELEASE) -> gsum (8 fan-in) -> flag[t].
    __syncthreads();
    if (t < NSTEPS - 1 && tid == 0) {
      unsigned prev = __hip_atomic_fetch_add(ga, 1u, __ATOMIC_RELEASE,
                                             __HIP_MEMORY_SCOPE_AGENT);
      if ((prev & 31u) == 31u) {        // 32nd arrival of this step on this line
        (void)__hip_atomic_load(ga, __ATOMIC_ACQUIRE, __HIP_MEMORY_SCOPE_AGENT);
        unsigned p2 = __hip_atomic_fetch_add(gsum, 1u, __ATOMIC_RELEASE,
                                             __HIP_MEMORY_SCOPE_AGENT);
        if ((p2 & 7u) == 7u) {          // all 8 groups done
          (void)__hip_atomic_load(gsum, __ATOMIC_ACQUIRE, __HIP_MEMORY_SCOPE_AGENT);
          __hip_atomic_store(flags + t * 16, 1u, __ATOMIC_RELEASE,
                             __HIP_MEMORY_SCOPE_AGENT);
        }
      }
    }
  }
}

// ---- head ---------------------------------------------------------------
__global__ void feat_kernel(const bf16* __restrict__ hb0, const int* __restrict__ s1,
                            const int* __restrict__ s2, float* __restrict__ HC,
                            float* __restrict__ H2T) {
  int a = blockIdx.x;
  int tid = threadIdx.x;
  __shared__ float red[256];
  const bf16* h1r = hb0 + (size_t)a * HID;
  const bf16* h2r = hb0 + (size_t)(a + 256) * HID;
  float l1 = (float)s1[a] * (1.f / 128.f);
  float l2 = (float)s2[a] * (1.f / 128.f);
  float dacc = 0.f;
  for (int k = tid; k < 1025; k += 256) {
    float v1 = (k < HID) ? (float)h1r[k] : l1;
    float v2 = (k < HID) ? (float)h2r[k] : l2;
    HC[(size_t)a * HC_W + k] = v1;
    HC[(size_t)a * HC_W + 1025 + k] = v2;
    HC[(size_t)a * HC_W + 2051 + k] = v1 * v2;
    H2T[(size_t)k * 256 + a] = v2;
    float d = v1 - v2;
    dacc += d * d;
  }
  red[tid] = dacc;
  __syncthreads();
  for (int s = 128; s > 0; s >>= 1) {
    if (tid < s) red[tid] += red[tid + s];
    __syncthreads();
  }
  if (tid == 0) HC[(size_t)a * HC_W + 2050] = red[0];
}

// 8 rows/block (grid 5 x 32) — r11-proven
__global__ void t1_kernel(const float* __restrict__ HC, const float* __restrict__ Wh,
                          float* __restrict__ T1) {
  int j = blockIdx.x * 256 + threadIdx.x;
  int a0 = blockIdx.y * 8;
  __shared__ float sh[8][64];
  float acc[8];
#pragma unroll
  for (int r = 0; r < 8; ++r) acc[r] = 0.f;
  for (int kc = 0; kc < 1025; kc += 64) {
    int kn = (1025 - kc < 64) ? (1025 - kc) : 64;
    for (int idx = threadIdx.x; idx < 512; idx += 256) {
      int r = idx >> 6, kk = idx & 63;
      sh[r][kk] = (kk < kn) ? HC[(size_t)(a0 + r) * HC_W + kc + kk] : 0.f;
    }
    __syncthreads();
    if (j < 1025) {
      for (int kk = 0; kk < kn; ++kk) {
        float w = Wh[(size_t)(kc + kk) * 1025 + j];
#pragma unroll
        for (int r = 0; r < 8; ++r) acc[r] += sh[r][kk] * w;
      }
    }
    __syncthreads();
  }
  if (j < 1025) {
    for (int r = 0; r < 8; ++r) T1[(size_t)(a0 + r) * 1025 + j] = acc[r];
  }
}

__global__ void inter_kernel(const float* __restrict__ T1, const float* __restrict__ H2T,
                             float* __restrict__ HC) {
  int a0 = blockIdx.x * 8;
  int b = threadIdx.x;
  __shared__ float sT[8][1025];
  for (int idx = threadIdx.x; idx < 8 * 1025; idx += 256) {
    int r = idx / 1025, k = idx - r * 1025;
    sT[r][k] = T1[(size_t)(a0 + r) * 1025 + k];
  }
  __syncthreads();
  float acc[8];
#pragma unroll
  for (int r = 0; r < 8; ++r) acc[r] = 0.f;
  for (int k = 0; k < 1025; ++k) {
    float v = H2T[(size_t)k * 256 + b];
#pragma unroll
    for (int r = 0; r < 8; ++r) acc[r] += sT[r][k] * v;
  }
#pragma unroll
  for (int r = 0; r < 8; ++r)
    HC[(size_t)(a0 + r) * HC_W + 3076 + b] = acc[r];
}

__global__ void e1_kernel(const float* __restrict__ HC, const float* __restrict__ W1,
                          const float* __restrict__ b1, float* __restrict__ E1) {
  int a0 = blockIdx.x * 8;
  int j = blockIdx.y * 256 + threadIdx.x;
  __shared__ float sh[8][128];
  float acc[8];
#pragma unroll
  for (int r = 0; r < 8; ++r) acc[r] = 0.f;
  for (int kc = 0; kc < HC_W; kc += 128) {
    int kn = (HC_W - kc < 128) ? (HC_W - kc) : 128;
    for (int idx = threadIdx.x; idx < 1024; idx += 256) {
      int r = idx >> 7, kk = idx & 127;
      sh[r][kk] = (kk < kn) ? HC[(size_t)(a0 + r) * HC_W + kc + kk] : 0.f;
    }
    __syncthreads();
    for (int kk = 0; kk < kn; ++kk) {
      float w = W1[(size_t)(kc + kk) * 512 + j];
#pragma unroll
      for (int r = 0; r < 8; ++r) acc[r] += sh[r][kk] * w;
    }
    __syncthreads();
  }
  float bj = b1[j];
#pragma unroll
  for (int r = 0; r < 8; ++r)
    E1[(size_t)(a0 + r) * 512 + j] = fmaxf(acc[r] + bj, 0.f);
}

__global__ void out_kernel(const float* __restrict__ E1, const float* __restrict__ W2,
                           const float* __restrict__ b2, float* __restrict__ out) {
  int a = threadIdx.x;
  float a0 = 0.f, a1 = 0.f;
  const float* e = E1 + (size_t)a * 512;
  for (int k = 0; k < 512; ++k) {
    float v = e[k];
    a0 += v * W2[2 * k];
    a1 += v * W2[2 * k + 1];
  }
  out[2 * a] = a0 + b2[0];
  out[2 * a + 1] = a1 + b2[1];
}

// ---- host ---------------------------------------------------------------
extern "C" void kernel_launch(void* const* d_in, const int* in_sizes, int n_in,
                              void* d_out, int out_size, void* d_ws, size_t ws_size,
                              hipStream_t stream) {
  const int*   input1 = (const int*)d_in[0];
  const int*   input2 = (const int*)d_in[1];
  const int*   seql1  = (const int*)d_in[2];
  const int*   seql2  = (const int*)d_in[3];
  const float* emb    = (const float*)d_in[4];
  const float* lk     = (const float*)d_in[5];
  const float* lbias  = (const float*)d_in[6];
  const float* c1i    = (const float*)d_in[7];
  const float* h1i    = (const float*)d_in[8];
  const float* c2i    = (const float*)d_in[9];
  const float* h2i    = (const float*)d_in[10];
  const float* W_h    = (const float*)d_in[11];
  const float* W1     = (const float*)d_in[12];
  const float* b1     = (const float*)d_in[13];
  const float* W2     = (const float*)d_in[14];
  const float* b2     = (const float*)d_in[15];

  char* ws = (char*)d_ws;
  bf16*     WbT   = (bf16*)(ws + WBT_OFF);
  bf16*     Xb    = (bf16*)(ws + XB_OFF);
  bf16*     Hb    = (bf16*)(ws + HB_OFF);
  float*    biasp = (float*)(ws + BIASP_OFF);
  float*    HC    = (float*)(ws + HC_OFF);
  float*    H2T   = (float*)(ws + H2T_OFF);
  float*    T1    = (float*)(ws + T1_OFF);
  float*    E1    = (float*)(ws + E1_OFF);
  unsigned* bar   = (unsigned*)(ws + BAR_OFF);

  pack_wbt<<<dim3(16, 1344), 256, 0, stream>>>(lk, WbT);
  pack_xb<<<dim3(512, 16), 320, 0, stream>>>(input1, input2, emb, Xb);
  pack_misc<<<2048, 256, 0, stream>>>(h1i, h2i, lbias, Hb, biasp, bar);

  void* kargs[] = { (void*)&Xb, (void*)&WbT, (void*)&Hb, (void*)&biasp,
                    (void*)&c1i, (void*)&c2i, (void*)&seql1, (void*)&seql2,
                    (void*)&bar };
  hipLaunchCooperativeKernel((void*)lstm_coop, dim3(256), dim3(256), kargs, 0, stream);

  feat_kernel<<<256, 256, 0, stream>>>(Hb, seql1, seql2, HC, H2T);
  t1_kernel<<<dim3(5, 32), 256, 0, stream>>>(HC, W_h, T1);
  inter_kernel<<<32, 256, 0, stream>>>(T1, H2T, HC);
  e1_kernel<<<dim3(32, 2), 256, 0, stream>>>(HC, W1, b1, E1);
  out_kernel<<<1, 256, 0, stream>>>(E1, W2, b2, (float*)d_out);
}

// Round 14
// 3574.314 us; speedup vs baseline: 1.6639x; 1.0011x over previous
//
#include <hip/hip_runtime.h>
#include <hip/hip_bf16.h>

typedef __bf16 bf16;
typedef __bf16 bf16x8 __attribute__((ext_vector_type(8)));
typedef float f32x4 __attribute__((ext_vector_type(4)));

#define N_ROWS   512      // rows 0..255 seq1, 256..511 seq2
#define HID      1024
#define KX       320      // EMB=300 padded to 320
#define KTOT     1344     // 320 + 1024
#define NSTEPS   128
#define EMB_D    300
#define HC_W     3332     // 1025+1025+1+1025+256

// workspace layout (bytes)
#define WBT_OFF   0UL          // bf16 [4096][1344]  (packed p2 order, transposed)
#define XB_OFF    11010048UL   // bf16 [128][512][320]
#define HB_OFF    52953088UL   // bf16 [2][512][1024]
#define BIASP_OFF 55050240UL   // f32  [4096] (packed p2 order)
#define HC_OFF    55066624UL   // f32  [256][3332]
#define H2T_OFF   58478592UL   // f32  [1025][256]
#define T1_OFF    59528192UL   // f32  [256][1025]
#define E1_OFF    60577792UL   // f32  [256][512]
// barrier region (dwords from BAR_OFF):
//   ga[g]   at dword g*16   (g=0..7)   8 monotonic arrive lines, 64B apart
//   gsum    at dword 128               monotonic summary line
//   flag[t] at dword 256 + t*16        per-step flag lines (fresh each step)
#define BAR_OFF   61102080UL

// ENVELOPE RULE (13 rounds of evidence): the cooperative kernel must use
// __launch_bounds__(256,2) with compiled VGPR <= 128 and static LDS <= 49KB
// (all passes: r5/r6/r9/r11/r13; (256,1)/high-VGPR/big-LDS variants silently
// no-op the coop launch: r3,r4,r10,r12). No multi-slot register staging
// arrays (r7/r8/r11: compiler remat -> 7x L2-fill blowup).

__device__ __forceinline__ float sigm(float x) { return 1.f / (1.f + __expf(-x)); }
__device__ __forceinline__ float tanh_fast(float x) {
  float xc = fminf(fmaxf(x, -15.f), 15.f);
  float e = __expf(2.f * xc);
  return (e - 1.f) / (e + 1.f);
}

// r14: LDS-only barrier — does NOT drain vmcnt, so global prefetch loads
// stay in flight across chunk boundaries (__syncthreads emits
// s_waitcnt vmcnt(0) before s_barrier, serializing a full load round-trip
// into every chunk iteration — the dominant stall r1..r13).
__device__ __forceinline__ void lds_barrier() {
  asm volatile("s_waitcnt lgkmcnt(0)" ::: "memory");
  __builtin_amdgcn_sched_barrier(0);
  __builtin_amdgcn_s_barrier();
  __builtin_amdgcn_sched_barrier(0);
}

// ---- pack kernels -------------------------------------------------------
// r13 packed order: p2 = cb*64 + g*16 + c  <->  orig col g*1024 + cb*16 + c
__global__ void pack_wbt(const float* __restrict__ lk, bf16* __restrict__ wbt) {
  int p = blockIdx.x * 256 + threadIdx.x;   // 0..4095
  int k = blockIdx.y;                        // 0..1343
  int cb = p >> 6, g = (p >> 4) & 3, c = p & 15;
  int oc = g * HID + cb * 16 + c;
  float v = 0.f;
  if (k < KX) { if (k < EMB_D) v = lk[(size_t)k * 4096 + oc]; }
  else v = lk[(size_t)(EMB_D + k - KX) * 4096 + oc];
  wbt[(size_t)p * KTOT + k] = (bf16)v;
}

// vectorized bf16x8 writes; block 320 = 8 timesteps x 40 e-groups (r11-proven)
__global__ void pack_xb(const int* __restrict__ in1, const int* __restrict__ in2,
                        const float* __restrict__ emb, bf16* __restrict__ xb) {
  int r = blockIdx.x;                        // 0..511
  int t = blockIdx.y * 8 + threadIdx.x / 40; // 0..127
  int e8 = threadIdx.x % 40;                 // 0..39 (8 elems each)
  int tok = (r < 256) ? in1[r * 128 + t] : in2[(r - 256) * 128 + t];
  const float* er = emb + (size_t)tok * EMB_D + e8 * 8;
  bf16x8 v;
  if (e8 < 37) {
#pragma unroll
    for (int i = 0; i < 8; ++i) v[i] = (bf16)er[i];
  } else {
#pragma unroll
    for (int i = 0; i < 8; ++i) {
      int e = e8 * 8 + i;
      v[i] = (e < EMB_D) ? (bf16)er[i] : (bf16)0.f;
    }
  }
  *reinterpret_cast<bf16x8*>(&xb[((size_t)t * N_ROWS + r) * KX + e8 * 8]) = v;
}

__global__ void pack_misc(const float* __restrict__ h1i, const float* __restrict__ h2i,
                          const float* __restrict__ bias, bf16* __restrict__ hb0,
                          float* __restrict__ biasp, unsigned* __restrict__ bar) {
  int idx = blockIdx.x * 256 + threadIdx.x;
  if (idx < N_ROWS * HID) {
    int r = idx >> 10, k = idx & 1023;
    float v = (r < 256) ? h1i[(size_t)r * HID + k] : h2i[(size_t)(r - 256) * HID + k];
    hb0[idx] = (bf16)v;
  }
  if (idx < 4096) {
    int cb = idx >> 6, g = (idx >> 4) & 3, c = idx & 15;
    biasp[idx] = bias[g * HID + cb * 16 + c];
    bar[idx] = 0u;   // reset all barrier lines (16 KB region) every launch
  }
}

// ---- cooperative LSTM recurrence ---------------------------------------
// grid 256 = 4 row-blocks x 64 col-groups. Block: 128 rows x 64 pcols
// (= all 4 gates of 16 cells, r13 packing). Wave w owns rows w*32..+31:
//   acc[mi][ni][q] = G[row=w*32+mi*16+(lane>>4)*4+q][pcol=ni*16+(lane&15)]
//   gate = ni, cell = cb*16 + (lane&15): cell update fully in-register.
// r14 = r13 with per-chunk __syncthreads -> lds_barrier (lgkmcnt-only):
// prefetch loads issued at kc stay in flight across the barrier; their
// results are vmcnt-waited only at the dependent ds_write next iteration.
// Step-boundary syncthreads (h-store drain) and grid-wait stay full.
__launch_bounds__(256, 2)
__global__ void lstm_coop(const bf16* __restrict__ xb, const bf16* __restrict__ wbt,
                          bf16* __restrict__ hb, const float* __restrict__ biasp,
                          const float* __restrict__ c1i, const float* __restrict__ c2i,
                          const int* __restrict__ s1, const int* __restrict__ s2,
                          unsigned* __restrict__ bar) {
  __shared__ bf16 As[2][128][64];    // 32 KB, XOR-swizzled 16B chunks
  __shared__ bf16 Bs[2][64][64];     // 16 KB  (total 48 KB)
  const int tid = threadIdx.x;
  const int wave = tid >> 6;
  const int lane = tid & 63;
  const int lrow = lane & 15;
  const int hi = lane >> 4;        // 0..3
  const int l7 = lane & 7;
  const int bid = blockIdx.x;
  const int rb = bid >> 6;         // 0..3
  const int cb = bid & 63;         // 0..63
  const int r0 = rb * 128;

  const int cellabs = cb * 16 + lrow;    // this lane's cell column (orig order)

  int slen[2][4];     // per (mi,q): row = r0 + wave*32 + mi*16 + hi*4 + q
#pragma unroll
  for (int mi = 0; mi < 2; ++mi)
#pragma unroll
    for (int q = 0; q < 4; ++q) {
      int rr = r0 + wave * 32 + mi * 16 + hi * 4 + q;
      slen[mi][q] = (rr < 256) ? s1[rr] : s2[rr - 256];
    }

  float creg[2][4];   // [mi][q] cell state, f32 in registers
#pragma unroll
  for (int mi = 0; mi < 2; ++mi)
#pragma unroll
    for (int q = 0; q < 4; ++q) {
      int rr = r0 + wave * 32 + mi * 16 + hi * 4 + q;
      const float* cbp = (rr < 256) ? (c1i + (size_t)rr * HID)
                                    : (c2i + (size_t)(rr - 256) * HID);
      creg[mi][q] = cbp[cellabs];
    }

  // bias folded into accumulator init: acc[.][ni] col = ni*16+lrow = gate ni
  float bv[4];
#pragma unroll
  for (int ni = 0; ni < 4; ++ni)
    bv[ni] = biasp[cb * 64 + ni * 16 + lrow];

  // staging thread mapping: A 128 rows x 8 chunks (2 threads/row, 4 chunks
  // each); B 64 rows x 8 chunks (4 threads/row, 2 chunks each). XOR swizzle:
  // chunk cc -> col ((cc ^ (row&7)) << 3).
  const int a_r = tid >> 1, a_cb = (tid & 1) * 4;
  const int b_r = tid >> 2, b_cb = (tid & 3) * 2;

  bf16x8 ra[4], rbv2[2];
  auto issue_loads = [&](int nt, int nkc) {
    const bf16* asrc = (nkc < 5)
        ? (xb + ((size_t)nt * N_ROWS + r0 + a_r) * KX + nkc * 64 + a_cb * 8)
        : (hb + ((size_t)(nt & 1) << 19) + ((size_t)(r0 + a_r) << 10) +
           (nkc * 64 - KX) + a_cb * 8);
#pragma unroll
    for (int q = 0; q < 4; ++q)
      ra[q] = *reinterpret_cast<const bf16x8*>(asrc + q * 8);
    const bf16* bsrc = wbt + (size_t)(cb * 64 + b_r) * KTOT + nkc * 64 + b_cb * 8;
#pragma unroll
    for (int q = 0; q < 2; ++q)
      rbv2[q] = *reinterpret_cast<const bf16x8*>(bsrc + q * 8);
  };
  auto stage_to = [&](int buf) {
#pragma unroll
    for (int q = 0; q < 4; ++q)
      *reinterpret_cast<bf16x8*>(&As[buf][a_r][((a_cb + q) ^ (a_r & 7)) << 3]) = ra[q];
#pragma unroll
    for (int q = 0; q < 2; ++q)
      *reinterpret_cast<bf16x8*>(&Bs[buf][b_r][((b_cb + q) ^ (b_r & 7)) << 3]) = rbv2[q];
  };

  // prologue: buf0 <- chunk 0 (t=0, x); regs <- chunk 1
  issue_loads(0, 0);
  stage_to(0);
  issue_loads(0, 1);
  __syncthreads();
  int db = 0;

  unsigned* ga    = bar + (bid & 7) * 16;   // own group arrive line (64B apart)
  unsigned* gsum  = bar + 128;              // summary line
  unsigned* flags = bar + 256;              // flag[t] at flags + t*16

  for (int t = 0; t < NSTEPS; ++t) {
    f32x4 acc[2][4];
#pragma unroll
    for (int mi = 0; mi < 2; ++mi)
#pragma unroll
      for (int ni = 0; ni < 4; ++ni)
        acc[mi][ni] = f32x4{bv[ni], bv[ni], bv[ni], bv[ni]};

    for (int kc = 0; kc < 21; ++kc) {
      // stage chunk kc+1 (regs invariant) into the other buffer
      stage_to(db ^ 1);

      // grid wait: peers' h(t) must be visible before the first h-load ISSUE
      // (nkc=5, issued this iteration). x-chunks 0..2 covered the latency.
      if (kc == 3 && t > 0) {
        if (tid == 0) {
          const unsigned* fl = flags + (t - 1) * 16;
          while (__hip_atomic_load(fl, __ATOMIC_RELAXED, __HIP_MEMORY_SCOPE_AGENT) == 0u)
            __builtin_amdgcn_s_sleep(2);
          (void)__hip_atomic_load(fl, __ATOMIC_ACQUIRE, __HIP_MEMORY_SCOPE_AGENT);
        }
        __syncthreads();
      }

      // issue loads for chunk kc+2 (wraps into next step's x-chunks)
      {
        int nkc = kc + 2, nt = t;
        if (nkc > 20) { nkc -= 21; ++nt; }
        if (nt < NSTEPS) issue_loads(nt, nkc);
      }

      // compute chunk kc from buf[db]: per ks, 2 A-frags + 4 B-frags, 8 MFMAs
#pragma unroll
      for (int ks = 0; ks < 2; ++ks) {
        const int cs = (((ks << 2) | hi) ^ l7) << 3;
        bf16x8 af[2], bfv[4];
#pragma unroll
        for (int mi = 0; mi < 2; ++mi)
          af[mi] = *reinterpret_cast<const bf16x8*>(
              &As[db][wave * 32 + mi * 16 + lrow][cs]);
#pragma unroll
        for (int ni = 0; ni < 4; ++ni)
          bfv[ni] = *reinterpret_cast<const bf16x8*>(&Bs[db][ni * 16 + lrow][cs]);
#pragma unroll
        for (int mi = 0; mi < 2; ++mi)
#pragma unroll
          for (int ni = 0; ni < 4; ++ni)
            acc[mi][ni] = __builtin_amdgcn_mfma_f32_16x16x32_bf16(
                af[mi], bfv[ni], acc[mi][ni], 0, 0, 0);
      }
      lds_barrier();   // lgkmcnt-only: prefetch loads stay in flight
      db ^= 1;
    }

    // cell update: lane owns 8 rows x 1 cell, all 4 gates in-register (g=ni)
    {
      const size_t curo = (size_t)(t & 1) << 19;
      const bf16* hc = hb + curo;
      bf16* hnb = hb + (curo ^ ((size_t)1 << 19));
#pragma unroll
      for (int mi = 0; mi < 2; ++mi)
#pragma unroll
        for (int q = 0; q < 4; ++q) {
          float ig = acc[mi][0][q];
          float jg = acc[mi][1][q];
          float fg = acc[mi][2][q];
          float og = acc[mi][3][q];
          float cn = sigm(fg + 1.f) * creg[mi][q] + sigm(ig) * tanh_fast(jg);
          float hv = tanh_fast(cn) * sigm(og);
          int rr = r0 + wave * 32 + mi * 16 + hi * 4 + q;
          size_t off = ((size_t)rr << 10) + cellabs;
          float ho;
          if (t < slen[mi][q]) { creg[mi][q] = cn; ho = hv; }
          else ho = (float)hc[off];
          hnb[off] = (bf16)ho;
        }
    }

    // arrive: full __syncthreads (drains h stores, vmcnt(0)) then hierarchical
    // release chain: ga (32 fan-in, RELEASE) -> gsum (8 fan-in) -> flag[t].
    __syncthreads();
    if (t < NSTEPS - 1 && tid == 0) {
      unsigned prev = __hip_atomic_fetch_add(ga, 1u, __ATOMIC_RELEASE,
                                             __HIP_MEMORY_SCOPE_AGENT);
      if ((prev & 31u) == 31u) {        // 32nd arrival of this step on this line
        (void)__hip_atomic_load(ga, __ATOMIC_ACQUIRE, __HIP_MEMORY_SCOPE_AGENT);
        unsigned p2 = __hip_atomic_fetch_add(gsum, 1u, __ATOMIC_RELEASE,
                                             __HIP_MEMORY_SCOPE_AGENT);
        if ((p2 & 7u) == 7u) {          // all 8 groups done
          (void)__hip_atomic_load(gsum, __ATOMIC_ACQUIRE, __HIP_MEMORY_SCOPE_AGENT);
          __hip_atomic_store(flags + t * 16, 1u, __ATOMIC_RELEASE,
                             __HIP_MEMORY_SCOPE_AGENT);
        }
      }
    }
  }
}

// ---- head ---------------------------------------------------------------
__global__ void feat_kernel(const bf16* __restrict__ hb0, const int* __restrict__ s1,
                            const int* __restrict__ s2, float* __restrict__ HC,
                            float* __restrict__ H2T) {
  int a = blockIdx.x;
  int tid = threadIdx.x;
  __shared__ float red[256];
  const bf16* h1r = hb0 + (size_t)a * HID;
  const bf16* h2r = hb0 + (size_t)(a + 256) * HID;
  float l1 = (float)s1[a] * (1.f / 128.f);
  float l2 = (float)s2[a] * (1.f / 128.f);
  float dacc = 0.f;
  for (int k = tid; k < 1025; k += 256) {
    float v1 = (k < HID) ? (float)h1r[k] : l1;
    float v2 = (k < HID) ? (float)h2r[k] : l2;
    HC[(size_t)a * HC_W + k] = v1;
    HC[(size_t)a * HC_W + 1025 + k] = v2;
    HC[(size_t)a * HC_W + 2051 + k] = v1 * v2;
    H2T[(size_t)k * 256 + a] = v2;
    float d = v1 - v2;
    dacc += d * d;
  }
  red[tid] = dacc;
  __syncthreads();
  for (int s = 128; s > 0; s >>= 1) {
    if (tid < s) red[tid] += red[tid + s];
    __syncthreads();
  }
  if (tid == 0) HC[(size_t)a * HC_W + 2050] = red[0];
}

// 8 rows/block (grid 5 x 32) — r11-proven
__global__ void t1_kernel(const float* __restrict__ HC, const float* __restrict__ Wh,
                          float* __restrict__ T1) {
  int j = blockIdx.x * 256 + threadIdx.x;
  int a0 = blockIdx.y * 8;
  __shared__ float sh[8][64];
  float acc[8];
#pragma unroll
  for (int r = 0; r < 8; ++r) acc[r] = 0.f;
  for (int kc = 0; kc < 1025; kc += 64) {
    int kn = (1025 - kc < 64) ? (1025 - kc) : 64;
    for (int idx = threadIdx.x; idx < 512; idx += 256) {
      int r = idx >> 6, kk = idx & 63;
      sh[r][kk] = (kk < kn) ? HC[(size_t)(a0 + r) * HC_W + kc + kk] : 0.f;
    }
    __syncthreads();
    if (j < 1025) {
      for (int kk = 0; kk < kn; ++kk) {
        float w = Wh[(size_t)(kc + kk) * 1025 + j];
#pragma unroll
        for (int r = 0; r < 8; ++r) acc[r] += sh[r][kk] * w;
      }
    }
    __syncthreads();
  }
  if (j < 1025) {
    for (int r = 0; r < 8; ++r) T1[(size_t)(a0 + r) * 1025 + j] = acc[r];
  }
}

__global__ void inter_kernel(const float* __restrict__ T1, const float* __restrict__ H2T,
                             float* __restrict__ HC) {
  int a0 = blockIdx.x * 8;
  int b = threadIdx.x;
  __shared__ float sT[8][1025];
  for (int idx = threadIdx.x; idx < 8 * 1025; idx += 256) {
    int r = idx / 1025, k = idx - r * 1025;
    sT[r][k] = T1[(size_t)(a0 + r) * 1025 + k];
  }
  __syncthreads();
  float acc[8];
#pragma unroll
  for (int r = 0; r < 8; ++r) acc[r] = 0.f;
  for (int k = 0; k < 1025; ++k) {
    float v = H2T[(size_t)k * 256 + b];
#pragma unroll
    for (int r = 0; r < 8; ++r) acc[r] += sT[r][k] * v;
  }
#pragma unroll
  for (int r = 0; r < 8; ++r)
    HC[(size_t)(a0 + r) * HC_W + 3076 + b] = acc[r];
}

__global__ void e1_kernel(const float* __restrict__ HC, const float* __restrict__ W1,
                          const float* __restrict__ b1, float* __restrict__ E1) {
  int a0 = blockIdx.x * 8;
  int j = blockIdx.y * 256 + threadIdx.x;
  __shared__ float sh[8][128];
  float acc[8];
#pragma unroll
  for (int r = 0; r < 8; ++r) acc[r] = 0.f;
  for (int kc = 0; kc < HC_W; kc += 128) {
    int kn = (HC_W - kc < 128) ? (HC_W - kc) : 128;
    for (int idx = threadIdx.x; idx < 1024; idx += 256) {
      int r = idx >> 7, kk = idx & 127;
      sh[r][kk] = (kk < kn) ? HC[(size_t)(a0 + r) * HC_W + kc + kk] : 0.f;
    }
    __syncthreads();
    for (int kk = 0; kk < kn; ++kk) {
      float w = W1[(size_t)(kc + kk) * 512 + j];
#pragma unroll
      for (int r = 0; r < 8; ++r) acc[r] += sh[r][kk] * w;
    }
    __syncthreads();
  }
  float bj = b1[j];
#pragma unroll
  for (int r = 0; r < 8; ++r)
    E1[(size_t)(a0 + r) * 512 + j] = fmaxf(acc[r] + bj, 0.f);
}

__global__ void out_kernel(const float* __restrict__ E1, const float* __restrict__ W2,
                           const float* __restrict__ b2, float* __restrict__ out) {
  int a = threadIdx.x;
  float a0 = 0.f, a1 = 0.f;
  const float* e = E1 + (size_t)a * 512;
  for (int k = 0; k < 512; ++k) {
    float v = e[k];
    a0 += v * W2[2 * k];
    a1 += v * W2[2 * k + 1];
  }
  out[2 * a] = a0 + b2[0];
  out[2 * a + 1] = a1 + b2[1];
}

// ---- host ---------------------------------------------------------------
extern "C" void kernel_launch(void* const* d_in, const int* in_sizes, int n_in,
                              void* d_out, int out_size, void* d_ws, size_t ws_size,
                              hipStream_t stream) {
  const int*   input1 = (const int*)d_in[0];
  const int*   input2 = (const int*)d_in[1];
  const int*   seql1  = (const int*)d_in[2];
  const int*   seql2  = (const int*)d_in[3];
  const float* emb    = (const float*)d_in[4];
  const float* lk     = (const float*)d_in[5];
  const float* lbias  = (const float*)d_in[6];
  const float* c1i    = (const float*)d_in[7];
  const float* h1i    = (const float*)d_in[8];
  const float* c2i    = (const float*)d_in[9];
  const float* h2i    = (const float*)d_in[10];
  const float* W_h    = (const float*)d_in[11];
  const float* W1     = (const float*)d_in[12];
  const float* b1     = (const float*)d_in[13];
  const float* W2     = (const float*)d_in[14];
  const float* b2     = (const float*)d_in[15];

  char* ws = (char*)d_ws;
  bf16*     WbT   = (bf16*)(ws + WBT_OFF);
  bf16*     Xb    = (bf16*)(ws + XB_OFF);
  bf16*     Hb    = (bf16*)(ws + HB_OFF);
  float*    biasp = (float*)(ws + BIASP_OFF);
  float*    HC    = (float*)(ws + HC_OFF);
  float*    H2T   = (float*)(ws + H2T_OFF);
  float*    T1    = (float*)(ws + T1_OFF);
  float*    E1    = (float*)(ws + E1_OFF);
  unsigned* bar   = (unsigned*)(ws + BAR_OFF);

  pack_wbt<<<dim3(16, 1344), 256, 0, stream>>>(lk, WbT);
  pack_xb<<<dim3(512, 16), 320, 0, stream>>>(input1, input2, emb, Xb);
  pack_misc<<<2048, 256, 0, stream>>>(h1i, h2i, lbias, Hb, biasp, bar);

  void* kargs[] = { (void*)&Xb, (void*)&WbT, (void*)&Hb, (void*)&biasp,
                    (void*)&c1i, (void*)&c2i, (void*)&seql1, (void*)&seql2,
                    (void*)&bar };
  hipLaunchCooperativeKernel((void*)lstm_coop, dim3(256), dim3(256), kargs, 0, stream);

  feat_kernel<<<256, 256, 0, stream>>>(Hb, seql1, seql2, HC, H2T);
  t1_kernel<<<dim3(5, 32), 256, 0, stream>>>(HC, W_h, T1);
  inter_kernel<<<32, 256, 0, stream>>>(T1, H2T, HC);
  e1_kernel<<<dim3(32, 2), 256, 0, stream>>>(HC, W1, b1, E1);
  out_kernel<<<1, 256, 0, stream>>>(E1, W2, b2, (float*)d_out);
}